// Round 4
// baseline (2035.608 us; speedup 1.0000x reference)
//
#include <hip/hip_runtime.h>

// HeteroSAGE encoder, fp32 end-to-end.
// Phases: CSR build (once per relation, reused across layers) -> projections ->
// per layer: {aggregate(mean) x2, fused dual-GEMM x2 (+BN stats), BN prep, BN apply x2}.
// All scratch in static __device__ globals (no d_ws dependence, no dynamic LDS).
// GEMMs write to separate out-buffers: the column-split blocks (blockIdx.y) each read
// ALL K columns of X1/X2, so in-place output would race across column-half blocks.

#define NN 100000
#define EE 600000
#define HH 128
#define LL 2
#define EPSV 1e-5f

// ---------------- static device scratch (BSS; fully rewritten every call) ----------------
__device__ float g_bufU[(size_t)NN * HH];   // aggregate(user <- items)
__device__ float g_bufI[(size_t)NN * HH];   // aggregate(item <- users)
__device__ float g_outU[(size_t)NN * HH];   // GEMM output (pre-BN)
__device__ float g_outI[(size_t)NN * HH];
__device__ float g_statsU[4 * HH];          // sum[H], sumsq[H], scale[H], shift[H]
__device__ float g_statsI[4 * HH];
__device__ int g_row_ui[NN + 1];
__device__ int g_cur_ui[NN];
__device__ int g_src_ui[EE];
__device__ int g_row_iu[NN + 1];
__device__ int g_cur_iu[NN];
__device__ int g_src_iu[EE];
__device__ int g_bsum[256];

// ---------------- CSR build ----------------
__global__ void k_count(const int* __restrict__ dst, int* __restrict__ cnt) {
  int i = blockIdx.x * blockDim.x + threadIdx.x;
  int stride = gridDim.x * blockDim.x;
  for (; i < EE; i += stride) atomicAdd(&cnt[dst[i]], 1);
}

__global__ void k_block_sum(const int* __restrict__ cnt, int* __restrict__ bsum) {
  __shared__ int s[1024];
  int i = blockIdx.x * 1024 + threadIdx.x;
  s[threadIdx.x] = (i < NN) ? cnt[i] : 0;
  __syncthreads();
  for (int o = 512; o > 0; o >>= 1) {
    if (threadIdx.x < o) s[threadIdx.x] += s[threadIdx.x + o];
    __syncthreads();
  }
  if (threadIdx.x == 0) bsum[blockIdx.x] = s[0];
}

__global__ void k_scan_bsum(int* __restrict__ bsum, int nb, int* __restrict__ row_ptr) {
  if (threadIdx.x == 0 && blockIdx.x == 0) {
    int acc = 0;
    for (int i = 0; i < nb; i++) { int t = bsum[i]; bsum[i] = acc; acc += t; }
    row_ptr[NN] = acc;  // == EE
  }
}

// cnt and cursor may alias (each thread reads its element before any write).
__global__ void k_scan_final(const int* cnt, const int* __restrict__ boff,
                             int* __restrict__ row_ptr, int* cursor) {
  __shared__ int s[1024];
  int i = blockIdx.x * 1024 + threadIdx.x;
  int v = (i < NN) ? cnt[i] : 0;
  s[threadIdx.x] = v;
  __syncthreads();
  for (int o = 1; o < 1024; o <<= 1) {
    int t = (threadIdx.x >= o) ? s[threadIdx.x - o] : 0;
    __syncthreads();
    s[threadIdx.x] += t;
    __syncthreads();
  }
  if (i < NN) {
    int excl = s[threadIdx.x] - v + boff[blockIdx.x];
    row_ptr[i] = excl;
    cursor[i]  = excl;
  }
}

__global__ void k_fill(const int* __restrict__ srcA, const int* __restrict__ dstA,
                       int* __restrict__ cursor, int* __restrict__ out_src) {
  int i = blockIdx.x * blockDim.x + threadIdx.x;
  int stride = gridDim.x * blockDim.x;
  for (; i < EE; i += stride) {
    int p = atomicAdd(&cursor[dstA[i]], 1);
    out_src[p] = srcA[i];
  }
}

// ---------------- segment mean (atomic-free; one wave per dst node) ----------------
__global__ void k_aggregate(const float* __restrict__ Hs, const int* __restrict__ row_ptr,
                            const int* __restrict__ sidx, float* __restrict__ out) {
  int lane = threadIdx.x & 63;
  int gw = (blockIdx.x * blockDim.x + threadIdx.x) >> 6;
  int nw = (gridDim.x * blockDim.x) >> 6;
  for (int node = gw; node < NN; node += nw) {
    int s = row_ptr[node], e = row_ptr[node + 1];
    float ax = 0.f, ay = 0.f;
    for (int j = s; j < e; j++) {
      int src = sidx[j];  // wave-uniform -> scalar load
      const float2 v = *reinterpret_cast<const float2*>(Hs + (size_t)src * HH + lane * 2);
      ax += v.x; ay += v.y;
    }
    int c = e - s;
    float inv = 1.0f / (float)(c > 0 ? c : 1);
    *reinterpret_cast<float2*>(out + (size_t)node * HH + lane * 2) = make_float2(ax * inv, ay * inv);
  }
}

// ---------------- dual GEMM: OUT[n,:] = bias + X1[n,:]@W1^T (+ X2[n,:]@W2^T), + BN stats --------
// Column-split: blockIdx.y in {0,1} picks cols [0,64) / [64,128). W^T tile for our 64 cols
// lives in STATIC shared mem: [K1+K2][64] fp32 <= 64 KiB exactly at KT=256. 512 thr = 8 waves;
// each wave owns 8 rows per tile; lane owns 1 col. Row activations are wave-uniform -> scalar
// (SMEM) addressing; inner loop is 8 v_fma + 1 conflict-free ds_read_b32 per k-step, which
// saturates the fp32 VALU FMA rate in steady state.
// NOTE: OUT must NOT alias X1/X2 (both column-half blocks read all K columns).
template <int K1, int K2>
__global__ __launch_bounds__(512)
void k_gemm_dual(const float* __restrict__ X1, const float* __restrict__ W1,
                 const float* __restrict__ bias,
                 const float* __restrict__ X2, const float* __restrict__ W2,
                 float* __restrict__ OUT, float* __restrict__ stats) {
  constexpr int KT = K1 + K2;
  __shared__ float WT[KT * 64];  // exactly 64 KiB at KT=256; first 1024 reused for reduction

  int tid = threadIdx.x;
  int ch = blockIdx.y;               // column half
  for (int idx = tid; idx < KT * 64; idx += 512) {
    int k = idx >> 6, cl = idx & 63;
    int c = ch * 64 + cl;
    WT[idx] = (k < K1) ? W1[c * K1 + k] : W2[c * K2 + (k - K1)];
  }
  __syncthreads();

  int lane = tid & 63;
  int widx = __builtin_amdgcn_readfirstlane(tid >> 6);  // force SGPR -> scalar row addressing
  int gw = blockIdx.x * 8 + widx;
  int nw = gridDim.x * 8;
  int c = ch * 64 + lane;

  float bb = bias[c];
  float s0 = 0.f, q0 = 0.f;

  const int ntiles = NN / 8;  // 12500
  for (int t = gw; t < ntiles; t += nw) {
    float acc[8];
#pragma unroll
    for (int r = 0; r < 8; r++) acc[r] = 0.f;

    const float* x1p = X1 + (size_t)t * 8 * K1;
#pragma unroll 4
    for (int k = 0; k < K1; k++) {
      float wv = WT[k * 64 + lane];
#pragma unroll
      for (int r = 0; r < 8; r++) acc[r] = fmaf(x1p[r * K1 + k], wv, acc[r]);
    }
    if (K2 > 0) {
      const float* x2p = X2 + (size_t)t * 8 * K2;
#pragma unroll 4
      for (int k = 0; k < K2; k++) {
        float wv = WT[(K1 + k) * 64 + lane];
#pragma unroll
        for (int r = 0; r < 8; r++) acc[r] = fmaf(x2p[r * K2 + k], wv, acc[r]);
      }
    }
    float* op = OUT + (size_t)t * 8 * HH + c;
#pragma unroll
    for (int r = 0; r < 8; r++) {
      float o0 = acc[r] + bb;
      if (stats) { s0 += o0; q0 += o0 * o0; }
      op[r * HH] = o0;
    }
  }

  if (stats) {
    // reduce the 8 waves' per-lane stats through LDS (reusing WT), then 128 atomics per block
    __syncthreads();                    // done reading WT weights
    float* red = &WT[0];                // reuse: [2][8][64] = 1024 floats
    red[widx * 64 + lane] = s0;
    red[512 + widx * 64 + lane] = q0;
    __syncthreads();
    if (widx == 0) {
      float ss = 0.f, qq = 0.f;
#pragma unroll
      for (int w8 = 0; w8 < 8; w8++) {
        ss += red[w8 * 64 + lane];
        qq += red[512 + w8 * 64 + lane];
      }
      atomicAdd(&stats[c], ss);
      atomicAdd(&stats[HH + c], qq);
    }
  }
}

// ---------------- BatchNorm (training-mode batch stats) + ReLU ----------------
__global__ void k_bn_prep(const float* __restrict__ stats, const float* __restrict__ g,
                          const float* __restrict__ b, float* __restrict__ scsh) {
  int c = threadIdx.x;
  if (c < HH) {
    const float invN = 1.0f / (float)NN;
    float mu = stats[c] * invN;
    float var = stats[HH + c] * invN - mu * mu;  // biased variance (matches reference)
    float sc = g[c] * rsqrtf(var + EPSV);
    scsh[c] = sc;
    scsh[HH + c] = b[c] - mu * sc;
  }
}

__global__ void k_bn_apply(const float* __restrict__ X, const float* __restrict__ scsh,
                           float* __restrict__ out) {
  int idx = blockIdx.x * blockDim.x + threadIdx.x;
  int stride = gridDim.x * blockDim.x;
  const int total = NN * HH / 4;
  for (; idx < total; idx += stride) {
    int c = (idx << 2) & 127;
    float4 x = reinterpret_cast<const float4*>(X)[idx];
    float4 sc = *reinterpret_cast<const float4*>(scsh + c);
    float4 sh = *reinterpret_cast<const float4*>(scsh + HH + c);
    float4 o;
    o.x = fmaxf(fmaf(x.x, sc.x, sh.x), 0.f);
    o.y = fmaxf(fmaf(x.y, sc.y, sh.y), 0.f);
    o.z = fmaxf(fmaf(x.z, sc.z, sh.z), 0.f);
    o.w = fmaxf(fmaf(x.w, sc.w, sh.w), 0.f);
    reinterpret_cast<float4*>(out)[idx] = o;
  }
}

extern "C" void kernel_launch(void* const* d_in, const int* in_sizes, int n_in,
                              void* d_out, int out_size, void* d_ws, size_t ws_size,
                              hipStream_t stream) {
  const float* x_user     = (const float*)d_in[0];
  const float* x_item     = (const float*)d_in[1];
  const float* lin_user_w = (const float*)d_in[2];
  const float* lin_user_b = (const float*)d_in[3];
  const float* lin_item_w = (const float*)d_in[4];
  const float* lin_item_b = (const float*)d_in[5];
  const float* Wl_ui      = (const float*)d_in[6];
  const float* bl_ui      = (const float*)d_in[7];
  const float* Wr_ui      = (const float*)d_in[8];
  const float* Wl_iu      = (const float*)d_in[9];
  const float* bl_iu      = (const float*)d_in[10];
  const float* Wr_iu      = (const float*)d_in[11];
  const float* bn_g_user  = (const float*)d_in[12];
  const float* bn_b_user  = (const float*)d_in[13];
  const float* bn_g_item  = (const float*)d_in[14];
  const float* bn_b_item  = (const float*)d_in[15];
  const int*   edge_ui    = (const int*)d_in[16];  // [2,E]: [0]=src(user), [1]=dst(item)
  const int*   edge_iu    = (const int*)d_in[17];  // [2,E]: [0]=src(item), [1]=dst(user)

  float* hu = (float*)d_out;               // [N,H]
  float* hi = hu + (size_t)NN * HH;        // [N,H]

  // resolve device-global scratch addresses (host-side query; capture-safe, no alloc)
  float *bufU, *bufI, *outU, *outI, *statsU, *statsI;
  int *row_ui, *cur_ui, *src_ui, *row_iu, *cur_iu, *src_iu, *bsum;
  hipGetSymbolAddress((void**)&bufU,   HIP_SYMBOL(g_bufU));
  hipGetSymbolAddress((void**)&bufI,   HIP_SYMBOL(g_bufI));
  hipGetSymbolAddress((void**)&outU,   HIP_SYMBOL(g_outU));
  hipGetSymbolAddress((void**)&outI,   HIP_SYMBOL(g_outI));
  hipGetSymbolAddress((void**)&statsU, HIP_SYMBOL(g_statsU));
  hipGetSymbolAddress((void**)&statsI, HIP_SYMBOL(g_statsI));
  hipGetSymbolAddress((void**)&row_ui, HIP_SYMBOL(g_row_ui));
  hipGetSymbolAddress((void**)&cur_ui, HIP_SYMBOL(g_cur_ui));
  hipGetSymbolAddress((void**)&src_ui, HIP_SYMBOL(g_src_ui));
  hipGetSymbolAddress((void**)&row_iu, HIP_SYMBOL(g_row_iu));
  hipGetSymbolAddress((void**)&cur_iu, HIP_SYMBOL(g_cur_iu));
  hipGetSymbolAddress((void**)&src_iu, HIP_SYMBOL(g_src_iu));
  hipGetSymbolAddress((void**)&bsum,   HIP_SYMBOL(g_bsum));

  const int NB = (NN + 1023) / 1024;  // 98 scan blocks

  // ---- CSR build, relation user->item (dst = item) ----
  hipMemsetAsync(cur_ui, 0, NN * 4, stream);
  k_count<<<1024, 256, 0, stream>>>(edge_ui + EE, cur_ui);
  k_block_sum<<<NB, 1024, 0, stream>>>(cur_ui, bsum);
  k_scan_bsum<<<1, 64, 0, stream>>>(bsum, NB, row_ui);
  k_scan_final<<<NB, 1024, 0, stream>>>(cur_ui, bsum, row_ui, cur_ui);
  k_fill<<<1024, 256, 0, stream>>>(edge_ui, edge_ui + EE, cur_ui, src_ui);

  // ---- CSR build, relation item->user (dst = user) ----
  hipMemsetAsync(cur_iu, 0, NN * 4, stream);
  k_count<<<1024, 256, 0, stream>>>(edge_iu + EE, cur_iu);
  k_block_sum<<<NB, 1024, 0, stream>>>(cur_iu, bsum);
  k_scan_bsum<<<1, 64, 0, stream>>>(bsum, NB, row_iu);
  k_scan_final<<<NB, 1024, 0, stream>>>(cur_iu, bsum, row_iu, cur_iu);
  k_fill<<<1024, 256, 0, stream>>>(edge_iu, edge_iu + EE, cur_iu, src_iu);

  // ---- input projections (no BN): hu = x_user@Wu^T+b, hi = x_item@Wi^T+b ----
  {
    dim3 g(256, 2);
    k_gemm_dual<64, 0><<<g, 512, 0, stream>>>(
        x_user, lin_user_w, lin_user_b, nullptr, nullptr, hu, nullptr);
    k_gemm_dual<128, 0><<<g, 512, 0, stream>>>(
        x_item, lin_item_w, lin_item_b, nullptr, nullptr, hi, nullptr);
  }

  // ---- layers ----
  for (int l = 0; l < LL; l++) {
    // aggregates use pre-update hu/hi
    k_aggregate<<<2048, 256, 0, stream>>>(hu, row_ui, src_ui, bufI);  // item <- mean(user srcs)
    k_aggregate<<<2048, 256, 0, stream>>>(hi, row_iu, src_iu, bufU);  // user <- mean(item srcs)
    hipMemsetAsync(statsI, 0, 2 * HH * 4, stream);
    hipMemsetAsync(statsU, 0, 2 * HH * 4, stream);
    dim3 g(256, 2);
    // out_i = agg_i@Wl_ui^T + bl + hi@Wr_ui^T   (to outI: no aliasing with inputs)
    k_gemm_dual<128, 128><<<g, 512, 0, stream>>>(
        bufI, Wl_ui + (size_t)l * HH * HH, bl_ui + (size_t)l * HH,
        hi, Wr_ui + (size_t)l * HH * HH, outI, statsI);
    // out_u = agg_u@Wl_iu^T + bl + hu@Wr_iu^T
    k_gemm_dual<128, 128><<<g, 512, 0, stream>>>(
        bufU, Wl_iu + (size_t)l * HH * HH, bl_iu + (size_t)l * HH,
        hu, Wr_iu + (size_t)l * HH * HH, outU, statsU);
    k_bn_prep<<<1, 128, 0, stream>>>(statsI, bn_g_item + l * HH, bn_b_item + l * HH, statsI + 2 * HH);
    k_bn_prep<<<1, 128, 0, stream>>>(statsU, bn_g_user + l * HH, bn_b_user + l * HH, statsU + 2 * HH);
    k_bn_apply<<<2048, 256, 0, stream>>>(outI, statsI + 2 * HH, hi);
    k_bn_apply<<<2048, 256, 0, stream>>>(outU, statsU + 2 * HH, hu);
  }
}

// Round 8
// 1582.766 us; speedup vs baseline: 1.2861x; 1.2861x over previous
//
#include <hip/hip_runtime.h>

// HeteroSAGE encoder. GEMMs via MFMA bf16 split (x = hi + lo; OUT = Xh*Wh + Xh*Wl + Xl*Wh,
// fp32 accumulate). All GEMM operands live as bf16 hi/lo PLANES (short arrays), produced by
// a W-prep kernel (weights), the aggregate epilogue (agg), and the bn_apply/proj epilogues (h).
// fp32 h additionally lives in d_out (consumed by aggregate gather + final output).
// No LDS in the GEMM: W-fragments are register-resident, X-fragments are direct 32B/lane
// global loads matching the 16x16x32 B-layout; D-fragment stores are 16B contiguous.
// NOTE on A/B fragment layout: correctness is invariant to the within-K32-slab lane/elem->k
// permutation because A and B are indexed with the SAME arithmetic (ks*32 + l4*8 + j); only
// the C/D mapping (HW-verified m89/m91) is load-bearing.

#define NN 100000
#define EE 600000
#define HH 128
#define LL 2
#define EPSV 1e-5f

typedef __attribute__((ext_vector_type(8))) short short8v;  // bf16x8 MFMA operand (4 VGPR)
typedef __attribute__((ext_vector_type(4))) short short4v;
typedef __attribute__((ext_vector_type(4))) float f32x4;    // MFMA accumulator

__device__ __forceinline__ unsigned short f2bf(float x) {   // fp32 -> bf16 RNE
  unsigned u = __float_as_uint(x);
  return (unsigned short)((u + 0x7FFFu + ((u >> 16) & 1u)) >> 16);
}
__device__ __forceinline__ float bf2f(unsigned short h) {
  return __uint_as_float((unsigned)h << 16);
}

// ---------------- static device scratch (fully rewritten every call) ----------------
__device__ float g_outU[(size_t)NN * HH];    // pre-BN GEMM output
__device__ float g_outI[(size_t)NN * HH];
__device__ short g_hpHU[(size_t)NN * HH];    // h planes (hi/lo), user/item
__device__ short g_hpLU[(size_t)NN * HH];
__device__ short g_hpHI[(size_t)NN * HH];
__device__ short g_hpLI[(size_t)NN * HH];
__device__ short g_apHU[(size_t)NN * HH];    // aggregate planes
__device__ short g_apLU[(size_t)NN * HH];
__device__ short g_apHI[(size_t)NN * HH];
__device__ short g_apLI[(size_t)NN * HH];
__device__ short g_WHpu[HH * 64],  g_WLpu[HH * 64];    // proj user weights [c][64]
__device__ short g_WHpi[HH * 128], g_WLpi[HH * 128];   // proj item weights [c][128]
__device__ short g_WHui[LL * HH * 256], g_WLui[LL * HH * 256];  // [c][k] k<128:Wl, k>=128:Wr
__device__ short g_WHiu[LL * HH * 256], g_WLiu[LL * HH * 256];
__device__ float g_statsU[4 * HH];
__device__ float g_statsI[4 * HH];
__device__ int g_row_ui[NN + 1];
__device__ int g_cur_ui[NN];
__device__ int g_src_ui[EE];
__device__ int g_row_iu[NN + 1];
__device__ int g_cur_iu[NN];
__device__ int g_src_iu[EE];
__device__ int g_bsum[256];

// ---------------- CSR build (unchanged, known-good) ----------------
__global__ void k_count(const int* __restrict__ dst, int* __restrict__ cnt) {
  int i = blockIdx.x * blockDim.x + threadIdx.x;
  int stride = gridDim.x * blockDim.x;
  for (; i < EE; i += stride) atomicAdd(&cnt[dst[i]], 1);
}

__global__ void k_block_sum(const int* __restrict__ cnt, int* __restrict__ bsum) {
  __shared__ int s[1024];
  int i = blockIdx.x * 1024 + threadIdx.x;
  s[threadIdx.x] = (i < NN) ? cnt[i] : 0;
  __syncthreads();
  for (int o = 512; o > 0; o >>= 1) {
    if (threadIdx.x < o) s[threadIdx.x] += s[threadIdx.x + o];
    __syncthreads();
  }
  if (threadIdx.x == 0) bsum[blockIdx.x] = s[0];
}

__global__ void k_scan_bsum(int* __restrict__ bsum, int nb, int* __restrict__ row_ptr) {
  if (threadIdx.x == 0 && blockIdx.x == 0) {
    int acc = 0;
    for (int i = 0; i < nb; i++) { int t = bsum[i]; bsum[i] = acc; acc += t; }
    row_ptr[NN] = acc;
  }
}

__global__ void k_scan_final(const int* cnt, const int* __restrict__ boff,
                             int* __restrict__ row_ptr, int* cursor) {
  __shared__ int s[1024];
  int i = blockIdx.x * 1024 + threadIdx.x;
  int v = (i < NN) ? cnt[i] : 0;
  s[threadIdx.x] = v;
  __syncthreads();
  for (int o = 1; o < 1024; o <<= 1) {
    int t = (threadIdx.x >= o) ? s[threadIdx.x - o] : 0;
    __syncthreads();
    s[threadIdx.x] += t;
    __syncthreads();
  }
  if (i < NN) {
    int excl = s[threadIdx.x] - v + boff[blockIdx.x];
    row_ptr[i] = excl;
    cursor[i]  = excl;
  }
}

__global__ void k_fill(const int* __restrict__ srcA, const int* __restrict__ dstA,
                       int* __restrict__ cursor, int* __restrict__ out_src) {
  int i = blockIdx.x * blockDim.x + threadIdx.x;
  int stride = gridDim.x * blockDim.x;
  for (; i < EE; i += stride) {
    int p = atomicAdd(&cursor[dstA[i]], 1);
    out_src[p] = srcA[i];
  }
}

// ---------------- weight prep: fp32 [128][K1](+[128][K2]) -> bf16 hi/lo planes [128][K1+K2] ----
__global__ void k_wprep(const float* __restrict__ W1, const float* __restrict__ W2,
                        int K1, int K2, short* __restrict__ WHo, short* __restrict__ WLo) {
  int KT2 = K1 + K2;
  int idx = blockIdx.x * blockDim.x + threadIdx.x;
  if (idx >= HH * KT2) return;
  int c = idx / KT2, k = idx - c * KT2;
  float w = (k < K1) ? W1[c * K1 + k] : W2[c * K2 + (k - K1)];
  unsigned short h = f2bf(w);
  WHo[idx] = (short)h;
  WLo[idx] = (short)f2bf(w - bf2f(h));
}

// ---------------- segment mean (gather fp32 h; emit bf16 hi/lo planes) ----------------
__global__ void k_aggregate(const float* __restrict__ Hs, const int* __restrict__ row_ptr,
                            const int* __restrict__ sidx,
                            short* __restrict__ AH, short* __restrict__ AL) {
  int lane = threadIdx.x & 63;
  int gw = (blockIdx.x * blockDim.x + threadIdx.x) >> 6;
  int nw = (gridDim.x * blockDim.x) >> 6;
  for (int node = gw; node < NN; node += nw) {
    int s = row_ptr[node], e = row_ptr[node + 1];
    float ax = 0.f, ay = 0.f;
    for (int j = s; j < e; j++) {
      int src = sidx[j];  // wave-uniform
      const float2 v = *reinterpret_cast<const float2*>(Hs + (size_t)src * HH + lane * 2);
      ax += v.x; ay += v.y;
    }
    int c = e - s;
    float inv = 1.0f / (float)(c > 0 ? c : 1);
    ax *= inv; ay *= inv;
    unsigned short hx = f2bf(ax), hy = f2bf(ay);
    unsigned pH = ((unsigned)hy << 16) | hx;
    unsigned pL = ((unsigned)f2bf(ay - bf2f(hy)) << 16) | (unsigned)f2bf(ax - bf2f(hx));
    *reinterpret_cast<unsigned*>(AH + (size_t)node * HH + lane * 2) = pH;
    *reinterpret_cast<unsigned*>(AL + (size_t)node * HH + lane * 2) = pL;
  }
}

// ---------------- MFMA layer GEMM: OUT = bias + X1@W[:, :128]^T + X2@W[:, 128:]^T -------------
// A = W (M=16 H-cols per frag), B = X^T (N=16 rows per frag). 4 waves/block; wave = 32 H-cols
// (2 m-grps) x 32 rows (2 n-grps). W-frags register-resident (128 VGPR), loaded once.
// D layout (m89/m91-verified): lane l, reg r -> D[(l>>4)*4+r][l&15]; D rows = H-cols,
// D cols = X-rows, so each lane stores 4 consecutive H-cols of one X-row = 16B dwordx4.
__global__ __launch_bounds__(256) void k_mfma_layer(
    const short* __restrict__ X1H, const short* __restrict__ X1L,
    const short* __restrict__ X2H, const short* __restrict__ X2L,
    const short* __restrict__ WH,  const short* __restrict__ WL,
    const float* __restrict__ bias, float* __restrict__ OUTF,
    float* __restrict__ stats) {
  const int tid = threadIdx.x, lane = tid & 63, wv = tid >> 6;
  const int l15 = lane & 15, l4 = lane >> 4;
  const int c0 = wv * 32;

  short8v Ah[2][8], Al[2][8];
#pragma unroll
  for (int mg = 0; mg < 2; ++mg) {
    const int col = c0 + mg * 16 + l15;
    const short* ph = WH + col * 256 + l4 * 8;
    const short* pl = WL + col * 256 + l4 * 8;
#pragma unroll
    for (int ks = 0; ks < 8; ++ks) {
      Ah[mg][ks] = *(const short8v*)(ph + ks * 32);
      Al[mg][ks] = *(const short8v*)(pl + ks * 32);
    }
  }

  f32x4 bb[2];
#pragma unroll
  for (int mg = 0; mg < 2; ++mg) bb[mg] = *(const f32x4*)(bias + c0 + mg * 16 + l4 * 4);

  float s[2][4] = {{0.f}}, q[2][4] = {{0.f}};

  const int ntiles = NN / 32;  // 3125, exact
  for (int t = blockIdx.x; t < ntiles; t += gridDim.x) {
    f32x4 acc[2][2];
#pragma unroll
    for (int ng = 0; ng < 2; ++ng)
#pragma unroll
      for (int mg = 0; mg < 2; ++mg) acc[ng][mg] = (f32x4){0.f, 0.f, 0.f, 0.f};

    const int n0 = t * 32 + l15;
#pragma unroll
    for (int ks = 0; ks < 8; ++ks) {
#pragma unroll
      for (int ng = 0; ng < 2; ++ng) {
        const int n = n0 + ng * 16;
        short8v Bh, Bl;
        if (ks < 4) {
          Bh = *(const short8v*)(X1H + (size_t)n * HH + ks * 32 + l4 * 8);
          Bl = *(const short8v*)(X1L + (size_t)n * HH + ks * 32 + l4 * 8);
        } else {
          Bh = *(const short8v*)(X2H + (size_t)n * HH + (ks - 4) * 32 + l4 * 8);
          Bl = *(const short8v*)(X2L + (size_t)n * HH + (ks - 4) * 32 + l4 * 8);
        }
#pragma unroll
        for (int mg = 0; mg < 2; ++mg) {
          acc[ng][mg] = __builtin_amdgcn_mfma_f32_16x16x32_bf16(Ah[mg][ks], Bh, acc[ng][mg], 0, 0, 0);
          acc[ng][mg] = __builtin_amdgcn_mfma_f32_16x16x32_bf16(Al[mg][ks], Bh, acc[ng][mg], 0, 0, 0);
          acc[ng][mg] = __builtin_amdgcn_mfma_f32_16x16x32_bf16(Ah[mg][ks], Bl, acc[ng][mg], 0, 0, 0);
        }
      }
    }
#pragma unroll
    for (int ng = 0; ng < 2; ++ng) {
      const int n = n0 + ng * 16;
#pragma unroll
      for (int mg = 0; mg < 2; ++mg) {
        f32x4 o = acc[ng][mg] + bb[mg];
#pragma unroll
        for (int r = 0; r < 4; ++r) { s[mg][r] += o[r]; q[mg][r] += o[r] * o[r]; }
        *(f32x4*)(OUTF + (size_t)n * HH + c0 + mg * 16 + l4 * 4) = o;
      }
    }
  }

  // column stats: reduce across the 16 lanes of each lane-group (same 4 m-cols), then atomics
#pragma unroll
  for (int mg = 0; mg < 2; ++mg)
#pragma unroll
    for (int r = 0; r < 4; ++r) {
      float ss = s[mg][r], qq = q[mg][r];
      for (int msk = 1; msk < 16; msk <<= 1) {
        ss += __shfl_xor(ss, msk);
        qq += __shfl_xor(qq, msk);
      }
      if (l15 == 0) {
        int m = c0 + mg * 16 + l4 * 4 + r;
        atomicAdd(&stats[m], ss);
        atomicAdd(&stats[HH + m], qq);
      }
    }
}

// ---------------- MFMA projection: OUT = bias + X@W^T (X fp32, converted in-register) ---------
// Writes fp32 h (to d_out) + bf16 hi/lo h-planes. No stats.
template <int K1>
__global__ __launch_bounds__(256) void k_mfma_proj(
    const float* __restrict__ X, const short* __restrict__ WH, const short* __restrict__ WL,
    const float* __restrict__ bias, float* __restrict__ OF32,
    short* __restrict__ OH, short* __restrict__ OL) {
  constexpr int KS = K1 / 32;
  const int tid = threadIdx.x, lane = tid & 63, wv = tid >> 6;
  const int l15 = lane & 15, l4 = lane >> 4;
  const int c0 = wv * 32;

  short8v Ah[2][KS], Al[2][KS];
#pragma unroll
  for (int mg = 0; mg < 2; ++mg) {
    const int col = c0 + mg * 16 + l15;
#pragma unroll
    for (int ks = 0; ks < KS; ++ks) {
      Ah[mg][ks] = *(const short8v*)(WH + col * K1 + ks * 32 + l4 * 8);
      Al[mg][ks] = *(const short8v*)(WL + col * K1 + ks * 32 + l4 * 8);
    }
  }
  f32x4 bb[2];
#pragma unroll
  for (int mg = 0; mg < 2; ++mg) bb[mg] = *(const f32x4*)(bias + c0 + mg * 16 + l4 * 4);

  const int ntiles = NN / 32;
  for (int t = blockIdx.x; t < ntiles; t += gridDim.x) {
    f32x4 acc[2][2];
#pragma unroll
    for (int ng = 0; ng < 2; ++ng)
#pragma unroll
      for (int mg = 0; mg < 2; ++mg) acc[ng][mg] = (f32x4){0.f, 0.f, 0.f, 0.f};

    const int n0 = t * 32 + l15;
#pragma unroll
    for (int ks = 0; ks < KS; ++ks) {
#pragma unroll
      for (int ng = 0; ng < 2; ++ng) {
        const int n = n0 + ng * 16;
        float xv[8];
        *(f32x4*)&xv[0] = *(const f32x4*)(X + (size_t)n * K1 + ks * 32 + l4 * 8);
        *(f32x4*)&xv[4] = *(const f32x4*)(X + (size_t)n * K1 + ks * 32 + l4 * 8 + 4);
        union { short sh[8]; short8v v; } hb, lb;
#pragma unroll
        for (int j = 0; j < 8; ++j) {
          unsigned short h = f2bf(xv[j]);
          hb.sh[j] = (short)h;
          lb.sh[j] = (short)f2bf(xv[j] - bf2f(h));
        }
#pragma unroll
        for (int mg = 0; mg < 2; ++mg) {
          acc[ng][mg] = __builtin_amdgcn_mfma_f32_16x16x32_bf16(Ah[mg][ks], hb.v, acc[ng][mg], 0, 0, 0);
          acc[ng][mg] = __builtin_amdgcn_mfma_f32_16x16x32_bf16(Al[mg][ks], hb.v, acc[ng][mg], 0, 0, 0);
          acc[ng][mg] = __builtin_amdgcn_mfma_f32_16x16x32_bf16(Ah[mg][ks], lb.v, acc[ng][mg], 0, 0, 0);
        }
      }
    }
#pragma unroll
    for (int ng = 0; ng < 2; ++ng) {
      const int n = n0 + ng * 16;
#pragma unroll
      for (int mg = 0; mg < 2; ++mg) {
        f32x4 o = acc[ng][mg] + bb[mg];
        short4v h4, lo4;
#pragma unroll
        for (int r = 0; r < 4; ++r) {
          unsigned short h = f2bf(o[r]);
          h4[r] = (short)h;
          lo4[r] = (short)f2bf(o[r] - bf2f(h));
        }
        const size_t off = (size_t)n * HH + c0 + mg * 16 + l4 * 4;
        *(f32x4*)(OF32 + off) = o;
        *(short4v*)(OH + off) = h4;
        *(short4v*)(OL + off) = lo4;
      }
    }
  }
}

// ---------------- BatchNorm prep + apply ----------------
__global__ void k_bn_prep(const float* __restrict__ stats, const float* __restrict__ g,
                          const float* __restrict__ b, float* __restrict__ scsh) {
  int c = threadIdx.x;
  if (c < HH) {
    const float invN = 1.0f / (float)NN;
    float mu = stats[c] * invN;
    float var = stats[HH + c] * invN - mu * mu;
    float sc = g[c] * rsqrtf(var + EPSV);
    scsh[c] = sc;
    scsh[HH + c] = b[c] - mu * sc;
  }
}

// reads pre-BN fp32, writes fp32 h (d_out) + bf16 hi/lo h-planes
__global__ void k_bn_apply(const float* __restrict__ X, const float* __restrict__ scsh,
                           float* __restrict__ outF, short* __restrict__ OH,
                           short* __restrict__ OL) {
  int idx = blockIdx.x * blockDim.x + threadIdx.x;
  int stride = gridDim.x * blockDim.x;
  const int total = NN * HH / 4;
  for (; idx < total; idx += stride) {
    int c = (idx << 2) & 127;
    float4 x = reinterpret_cast<const float4*>(X)[idx];
    float4 sc = *reinterpret_cast<const float4*>(scsh + c);
    float4 sh = *reinterpret_cast<const float4*>(scsh + HH + c);
    float ov[4];
    ov[0] = fmaxf(fmaf(x.x, sc.x, sh.x), 0.f);
    ov[1] = fmaxf(fmaf(x.y, sc.y, sh.y), 0.f);
    ov[2] = fmaxf(fmaf(x.z, sc.z, sh.z), 0.f);
    ov[3] = fmaxf(fmaf(x.w, sc.w, sh.w), 0.f);
    float4 o = make_float4(ov[0], ov[1], ov[2], ov[3]);
    reinterpret_cast<float4*>(outF)[idx] = o;
    short4v h4, lo4;
#pragma unroll
    for (int r = 0; r < 4; ++r) {
      unsigned short h = f2bf(ov[r]);
      h4[r] = (short)h;
      lo4[r] = (short)f2bf(ov[r] - bf2f(h));
    }
    *(short4v*)(OH + (size_t)idx * 4) = h4;
    *(short4v*)(OL + (size_t)idx * 4) = lo4;
  }
}

extern "C" void kernel_launch(void* const* d_in, const int* in_sizes, int n_in,
                              void* d_out, int out_size, void* d_ws, size_t ws_size,
                              hipStream_t stream) {
  const float* x_user     = (const float*)d_in[0];
  const float* x_item     = (const float*)d_in[1];
  const float* lin_user_w = (const float*)d_in[2];
  const float* lin_user_b = (const float*)d_in[3];
  const float* lin_item_w = (const float*)d_in[4];
  const float* lin_item_b = (const float*)d_in[5];
  const float* Wl_ui      = (const float*)d_in[6];
  const float* bl_ui      = (const float*)d_in[7];
  const float* Wr_ui      = (const float*)d_in[8];
  const float* Wl_iu      = (const float*)d_in[9];
  const float* bl_iu      = (const float*)d_in[10];
  const float* Wr_iu      = (const float*)d_in[11];
  const float* bn_g_user  = (const float*)d_in[12];
  const float* bn_b_user  = (const float*)d_in[13];
  const float* bn_g_item  = (const float*)d_in[14];
  const float* bn_b_item  = (const float*)d_in[15];
  const int*   edge_ui    = (const int*)d_in[16];
  const int*   edge_iu    = (const int*)d_in[17];

  float* hu = (float*)d_out;
  float* hi = hu + (size_t)NN * HH;

  float *outU, *outI, *statsU, *statsI;
  short *hpHU, *hpLU, *hpHI, *hpLI, *apHU, *apLU, *apHI, *apLI;
  short *WHpu, *WLpu, *WHpi, *WLpi, *WHui, *WLui, *WHiu, *WLiu;
  int *row_ui, *cur_ui, *src_ui, *row_iu, *cur_iu, *src_iu, *bsum;
  hipGetSymbolAddress((void**)&outU,  HIP_SYMBOL(g_outU));
  hipGetSymbolAddress((void**)&outI,  HIP_SYMBOL(g_outI));
  hipGetSymbolAddress((void**)&hpHU,  HIP_SYMBOL(g_hpHU));
  hipGetSymbolAddress((void**)&hpLU,  HIP_SYMBOL(g_hpLU));
  hipGetSymbolAddress((void**)&hpHI,  HIP_SYMBOL(g_hpHI));
  hipGetSymbolAddress((void**)&hpLI,  HIP_SYMBOL(g_hpLI));
  hipGetSymbolAddress((void**)&apHU,  HIP_SYMBOL(g_apHU));
  hipGetSymbolAddress((void**)&apLU,  HIP_SYMBOL(g_apLU));
  hipGetSymbolAddress((void**)&apHI,  HIP_SYMBOL(g_apHI));
  hipGetSymbolAddress((void**)&apLI,  HIP_SYMBOL(g_apLI));
  hipGetSymbolAddress((void**)&WHpu,  HIP_SYMBOL(g_WHpu));
  hipGetSymbolAddress((void**)&WLpu,  HIP_SYMBOL(g_WLpu));
  hipGetSymbolAddress((void**)&WHpi,  HIP_SYMBOL(g_WHpi));
  hipGetSymbolAddress((void**)&WLpi,  HIP_SYMBOL(g_WLpi));
  hipGetSymbolAddress((void**)&WHui,  HIP_SYMBOL(g_WHui));
  hipGetSymbolAddress((void**)&WLui,  HIP_SYMBOL(g_WLui));
  hipGetSymbolAddress((void**)&WHiu,  HIP_SYMBOL(g_WHiu));
  hipGetSymbolAddress((void**)&WLiu,  HIP_SYMBOL(g_WLiu));
  hipGetSymbolAddress((void**)&statsU, HIP_SYMBOL(g_statsU));
  hipGetSymbolAddress((void**)&statsI, HIP_SYMBOL(g_statsI));
  hipGetSymbolAddress((void**)&row_ui, HIP_SYMBOL(g_row_ui));
  hipGetSymbolAddress((void**)&cur_ui, HIP_SYMBOL(g_cur_ui));
  hipGetSymbolAddress((void**)&src_ui, HIP_SYMBOL(g_src_ui));
  hipGetSymbolAddress((void**)&row_iu, HIP_SYMBOL(g_row_iu));
  hipGetSymbolAddress((void**)&cur_iu, HIP_SYMBOL(g_cur_iu));
  hipGetSymbolAddress((void**)&src_iu, HIP_SYMBOL(g_src_iu));
  hipGetSymbolAddress((void**)&bsum,   HIP_SYMBOL(g_bsum));

  const int NB = (NN + 1023) / 1024;

  // ---- CSR build x2 ----
  hipMemsetAsync(cur_ui, 0, NN * 4, stream);
  k_count<<<1024, 256, 0, stream>>>(edge_ui + EE, cur_ui);
  k_block_sum<<<NB, 1024, 0, stream>>>(cur_ui, bsum);
  k_scan_bsum<<<1, 64, 0, stream>>>(bsum, NB, row_ui);
  k_scan_final<<<NB, 1024, 0, stream>>>(cur_ui, bsum, row_ui, cur_ui);
  k_fill<<<1024, 256, 0, stream>>>(edge_ui, edge_ui + EE, cur_ui, src_ui);

  hipMemsetAsync(cur_iu, 0, NN * 4, stream);
  k_count<<<1024, 256, 0, stream>>>(edge_iu + EE, cur_iu);
  k_block_sum<<<NB, 1024, 0, stream>>>(cur_iu, bsum);
  k_scan_bsum<<<1, 64, 0, stream>>>(bsum, NB, row_iu);
  k_scan_final<<<NB, 1024, 0, stream>>>(cur_iu, bsum, row_iu, cur_iu);
  k_fill<<<1024, 256, 0, stream>>>(edge_iu, edge_iu + EE, cur_iu, src_iu);

  // ---- weight prep (bf16 hi/lo planes) ----
  k_wprep<<<(HH * 64 + 255) / 256, 256, 0, stream>>>(lin_user_w, nullptr, 64, 0, WHpu, WLpu);
  k_wprep<<<(HH * 128 + 255) / 256, 256, 0, stream>>>(lin_item_w, nullptr, 128, 0, WHpi, WLpi);
  for (int l = 0; l < LL; l++) {
    k_wprep<<<(HH * 256 + 255) / 256, 256, 0, stream>>>(
        Wl_ui + (size_t)l * HH * HH, Wr_ui + (size_t)l * HH * HH, 128, 128,
        WHui + (size_t)l * HH * 256, WLui + (size_t)l * HH * 256);
    k_wprep<<<(HH * 256 + 255) / 256, 256, 0, stream>>>(
        Wl_iu + (size_t)l * HH * HH, Wr_iu + (size_t)l * HH * HH, 128, 128,
        WHiu + (size_t)l * HH * 256, WLiu + (size_t)l * HH * 256);
  }

  // ---- projections: h = x@W^T + b -> fp32 h (d_out) + h planes ----
  k_mfma_proj<64><<<512, 256, 0, stream>>>(x_user, WHpu, WLpu, lin_user_b, hu, hpHU, hpLU);
  k_mfma_proj<128><<<512, 256, 0, stream>>>(x_item, WHpi, WLpi, lin_item_b, hi, hpHI, hpLI);

  // ---- layers ----
  for (int l = 0; l < LL; l++) {
    k_aggregate<<<2048, 256, 0, stream>>>(hu, row_ui, src_ui, apHI, apLI);  // item <- mean(user)
    k_aggregate<<<2048, 256, 0, stream>>>(hi, row_iu, src_iu, apHU, apLU);  // user <- mean(item)
    hipMemsetAsync(statsI, 0, 2 * HH * 4, stream);
    hipMemsetAsync(statsU, 0, 2 * HH * 4, stream);
    k_mfma_layer<<<512, 256, 0, stream>>>(
        apHI, apLI, hpHI, hpLI,
        WHui + (size_t)l * HH * 256, WLui + (size_t)l * HH * 256,
        bl_ui + (size_t)l * HH, outI, statsI);
    k_mfma_layer<<<512, 256, 0, stream>>>(
        apHU, apLU, hpHU, hpLU,
        WHiu + (size_t)l * HH * 256, WLiu + (size_t)l * HH * 256,
        bl_iu + (size_t)l * HH, outU, statsU);
    k_bn_prep<<<1, 128, 0, stream>>>(statsI, bn_g_item + l * HH, bn_b_item + l * HH, statsI + 2 * HH);
    k_bn_prep<<<1, 128, 0, stream>>>(statsU, bn_g_user + l * HH, bn_b_user + l * HH, statsU + 2 * HH);
    k_bn_apply<<<2048, 256, 0, stream>>>(outI, statsI + 2 * HH, hi, hpHI, hpLI);
    k_bn_apply<<<2048, 256, 0, stream>>>(outU, statsU + 2 * HH, hu, hpHU, hpLU);
  }
}